// Round 14
// baseline (36.867 us; speedup 1.0000x reference)
//
#include <hip/hip_runtime.h>
#include <hip/hip_bf16.h>
#include <cstdint>

#define DEV_INLINE __device__ __forceinline__

typedef __attribute__((ext_vector_type(8))) short short8v;   // 8 bf16 (4 VGPRs)
typedef __attribute__((ext_vector_type(4))) float f32x4;
typedef __attribute__((ext_vector_type(2))) float v2f;       // packed fp32 pair

constexpr int BSZ = 2, NUM_Q = 256, NUM_K = 2048, D_IN = 512, D_ATT = 128;
constexpr float S_ATT = 0.08838834764831845f;   // 1/sqrt(128)
constexpr float C2 = 2.8853900817779268f;       // 2*log2(e): exp2(C2*x) = e^{2x}

DEV_INLINE uint16_t f2bf(float f) {  // fp32 -> bf16, RNE via HW convert
  return __builtin_bit_cast(uint16_t, static_cast<__bf16>(f));
}

DEV_INLINE float fast_exp2(float x) {
#if __has_builtin(__builtin_amdgcn_exp2f)
  return __builtin_amdgcn_exp2f(x);
#else
  return __expf(0.6931471805599453f * x);
#endif
}

// ---------------------------------------------------------------------------
// pack_w (64 blocks): fragment-packed Wt2, chunk (mat,cb,s) = 64 lanes x
// 8 bf16; lane l: cols cb*16+(l&15), k = s*32+(l>>4)*8+j. Block 0 also does
// vsumc[0] = sum(v_att)+b_att.
// ---------------------------------------------------------------------------
__global__ __launch_bounds__(256) void pack_w(
    const float* __restrict__ Wlq, const float* __restrict__ Wbq,
    const float* __restrict__ Wlk, const float* __restrict__ Wbk,
    const float* __restrict__ v_att, const float* __restrict__ b_att,
    uint16_t* __restrict__ Wt2, float* __restrict__ vsumc) {
  __shared__ float xs[256 * 17];  // 17 KB, +1 pad
  const int bid = blockIdx.x;
  const int t = threadIdx.x;

  const int mat = bid >> 5, cb = (bid >> 1) & 15, kh = bid & 1;
  const float* W = (mat == 0) ? (cb < 8 ? Wlq : Wbq) : (cb < 8 ? Wlk : Wbk);
  const int cbase = (cb & 7) * 16;

#pragma unroll
  for (int i = 0; i < 4; ++i) {
    const int fq = t + i * 256;          // 1024 quads
    const int k = fq >> 2, c4 = (fq & 3) * 4;
    const float4 v = *(const float4*)&W[(size_t)(kh * 256 + k) * D_ATT + cbase + c4];
    xs[k * 17 + c4 + 0] = v.x;
    xs[k * 17 + c4 + 1] = v.y;
    xs[k * 17 + c4 + 2] = v.z;
    xs[k * 17 + c4 + 3] = v.w;
  }
  __syncthreads();

#pragma unroll
  for (int i = 0; i < 2; ++i) {
    const int e = t + i * 256;
    const int sl = e >> 6, l = e & 63;
    const int kb_ = sl * 32 + (l >> 4) * 8;
    const int c = l & 15;
    uint16_t o[8];
#pragma unroll
    for (int j = 0; j < 8; ++j) o[j] = f2bf(xs[(kb_ + j) * 17 + c]);
    const int sg = kh * 8 + sl;
    *(uint4*)(Wt2 + ((size_t)(mat * 16 + cb) * 16 + sg) * 512 + l * 8) =
        *(const uint4*)o;
  }

  if (bid == 0 && t < 64) {
    float s = v_att[t] + v_att[t + 64];
#pragma unroll
    for (int off = 32; off >= 1; off >>= 1) s += __shfl_down(s, off);
    if (t == 0) vsumc[0] = s + b_att[0];
  }
}

// ---------------------------------------------------------------------------
// proj_gemm (576 blocks x 256 thr): [query;key] (4608x512 fp32 -> bf16 during
// LDS staging, HW RNE cvt) @ Wt2. Epilogue: eq = exp2(C2*ql) fp32;
// ek = bf16(exp2(C2*kl)); qb bf16 (xS_ATT); kb bf16.
// Block = 4 waves sharing ONE 16-row A-tile (XOR-swizzled);
// rt = bid>>1, ct2 = (bid&1)*4 + wave.
// Frag maps (validated r3-r13): A row=lane&15, k=(lane>>4)*8+j; B col=lane&15;
// C/D col=lane&15, row=(lane>>4)*4+reg.
// ---------------------------------------------------------------------------
__global__ __launch_bounds__(256) void proj_gemm(
    const float* __restrict__ Xq, const float* __restrict__ Xk,
    const uint16_t* __restrict__ Wt2,
    const float* __restrict__ b_lq, const float* __restrict__ b_bq,
    const float* __restrict__ b_lk, const float* __restrict__ b_bk,
    float* __restrict__ eq, uint16_t* __restrict__ qb,
    uint16_t* __restrict__ ek, uint16_t* __restrict__ kb) {
  __shared__ __align__(16) unsigned char alds[16 * 1024];  // 16 rows x 512 bf16
  const int bid = blockIdx.x;           // 0..575
  const int t = threadIdx.x;
  const int l = t & 63;
  const int rt = bid >> 1;              // 0..287 (row-tile of 16)
  const int ct2 = (bid & 1) * 4 + (t >> 6);  // 0..7

  const bool isq = rt < 32;
  const int mat = isq ? 0 : 1;
  const int row0 = isq ? rt * 16 : (rt - 32) * 16;  // local row in q/k buffers
  const float* src = (isq ? Xq : Xk) + (size_t)row0 * D_IN;

  // stage A-tile: 1024 bf16 16B-chunks; chunk f: row=f>>6, c=f&63 (8 elems)
#pragma unroll
  for (int i = 0; i < 4; ++i) {
    const int f = t + i * 256;
    const int row = f >> 6, c = f & 63;
    const float* s8 = src + (size_t)row * D_IN + c * 8;
    const float4 a = *(const float4*)s8;
    const float4 b = *(const float4*)(s8 + 4);
    uint16_t o[8];
    o[0] = f2bf(a.x); o[1] = f2bf(a.y); o[2] = f2bf(a.z); o[3] = f2bf(a.w);
    o[4] = f2bf(b.x); o[5] = f2bf(b.y); o[6] = f2bf(b.z); o[7] = f2bf(b.w);
    *(uint4*)(alds + row * 1024 + ((c ^ (row & 7)) << 4)) = *(const uint4*)o;
  }
  __syncthreads();

  const uint16_t* wbase =
      Wt2 + ((size_t)(mat * 16 + ct2 * 2) * 16) * 512 + l * 8;
  const int arow = l & 15;

  f32x4 acc0 = {0.f, 0.f, 0.f, 0.f}, acc1 = {0.f, 0.f, 0.f, 0.f};
#pragma unroll 8
  for (int s = 0; s < 16; ++s) {
    const int chunk = (s * 4 + (l >> 4)) ^ (arow & 7);
    const short8v a = *(const short8v*)(alds + arow * 1024 + (chunk << 4));
    const short8v b0 = *(const short8v*)(wbase + (size_t)s * 512);
    const short8v b1 = *(const short8v*)(wbase + (size_t)(16 + s) * 512);
    acc0 = __builtin_amdgcn_mfma_f32_16x16x32_bf16(a, b0, acc0, 0, 0, 0);
    acc1 = __builtin_amdgcn_mfma_f32_16x16x32_bf16(a, b1, acc1, 0, 0, 0);
  }

  const int lrow4 = (l >> 4) * 4;
#pragma unroll
  for (int half = 0; half < 2; ++half) {
    const f32x4 acc = half ? acc1 : acc0;
    const int cbb = ct2 * 32 + half * 16;  // wave-uniform col-block base
    const int cl = (cbb + (l & 15)) & 127;
    float bias;
    if (isq) bias = (cbb < 128) ? b_lq[cl] : b_bq[cl];
    else     bias = (cbb < 128) ? b_lk[cl] : b_bk[cl];
#pragma unroll
    for (int jr = 0; jr < 4; ++jr) {
      const int row = row0 + lrow4 + jr;
      const float val = acc[jr] + bias;
      if (isq) {
        if (cbb < 128) eq[row * D_ATT + cl] = fast_exp2(C2 * val);
        else           qb[row * D_ATT + cl] = f2bf(val * S_ATT);
      } else {
        if (cbb < 128) ek[row * D_ATT + cl] = f2bf(fast_exp2(C2 * val));
        else           kb[row * D_ATT + cl] = f2bf(val);
      }
    }
  }
}

// ---------------------------------------------------------------------------
// fused: out = cst - 2*sum_d v_d/(1+eq*ek) + qb.kb
// 1024 blocks x 256 thr = 4 waves; tile 16 q x 64 k; eq AND v via wave-
// uniform scalar loads; ek bf16 in LDS (swizzled). LDS 20 KB.
// Packed fp32 inner loop; 8-batch pair-reciprocal (1 rcp per 8 elems):
//   Q1=dd0*dd1, Q2=dd2*dd3, R=Q1*Q2, r=rcp(R.x*R.y), t={r*R.y,r*R.x},
//   iQ1=t*Q2, iQ2=t*Q1; 1/dd0 = iQ1*dd1, etc. (4-dd product <= 2^92, safe.)
// ---------------------------------------------------------------------------
__global__ __launch_bounds__(256) void fused_kernel(
    const float* __restrict__ eq_g, const uint16_t* __restrict__ qb_g,
    const uint16_t* __restrict__ ek_g, const uint16_t* __restrict__ kb_g,
    const float* __restrict__ v_att, const float* __restrict__ vsumc,
    float* __restrict__ out) {
  __shared__ __align__(16) unsigned char klds[64 * 256];  // ek bf16, swizzled
  __shared__ float sblds[16 * 64];                        // bilinear C, 4 KB

  const int tid = threadIdx.x;
  const int b = blockIdx.x >> 9;
  const int qt = (blockIdx.x >> 5) & 15;
  const int kt = blockIdx.x & 31;

  // --- stage ek tile (64 rows x 256B, XOR-swizzled 16B chunks) ---
  const uint4* ekg = (const uint4*)(ek_g + (size_t)(b * NUM_K + kt * 64) * D_ATT);
#pragma unroll
  for (int i = 0; i < 4; ++i) {
    const int f = tid + i * 256;
    const int kr = f >> 4, c = f & 15;
    *(uint4*)(klds + kr * 256 + ((c ^ (kr & 7)) << 4)) = ekg[f];
  }

  // --- bilinear via MFMA: wave w -> k-range [w*16, w*16+16) ---
  {
    const int l = tid & 63;
    const int w = tid >> 6;
    const uint16_t* ap =
        qb_g + (size_t)(b * NUM_Q + qt * 16 + (l & 15)) * D_ATT + (l >> 4) * 8;
    const uint16_t* bp =
        kb_g + (size_t)(b * NUM_K + kt * 64 + w * 16 + (l & 15)) * D_ATT + (l >> 4) * 8;
    f32x4 acc = {0.f, 0.f, 0.f, 0.f};
#pragma unroll
    for (int s = 0; s < 4; ++s) {
      const short8v a = *(const short8v*)(ap + s * 32);
      const short8v bb = *(const short8v*)(bp + s * 32);
      acc = __builtin_amdgcn_mfma_f32_16x16x32_bf16(a, bb, acc, 0, 0, 0);
    }
    const int col = w * 16 + (l & 15);
    const int r0 = (l >> 4) * 4;
#pragma unroll
    for (int jr = 0; jr < 4; ++jr) sblds[(r0 + jr) * 64 + col] = acc[jr];
  }
  __syncthreads();

  // --- linear path (packed fp32): thread = (k = tid&63, q-group tid>>6) ---
  const int k = tid & 63;
  const int w = tid >> 6;
  const int qoff =
      __builtin_amdgcn_readfirstlane((b * NUM_Q + qt * 16 + (tid >> 6) * 4) * D_ATT);
  const float* qbase = eq_g + qoff;

  const v2f one2 = {1.0f, 1.0f};
  v2f accp[4];
#pragma unroll
  for (int qq = 0; qq < 4; ++qq) accp[qq] = (v2f){0.f, 0.f};

#pragma unroll 2
  for (int d0 = 0; d0 < D_ATT; d0 += 8) {
    const int c = d0 >> 3;
    const uint4 ekv = *(const uint4*)(klds + k * 256 + ((c ^ (k & 7)) << 4));
    v2f ek2[4];
    ek2[0] = (v2f){__uint_as_float(ekv.x << 16), __uint_as_float(ekv.x & 0xffff0000u)};
    ek2[1] = (v2f){__uint_as_float(ekv.y << 16), __uint_as_float(ekv.y & 0xffff0000u)};
    ek2[2] = (v2f){__uint_as_float(ekv.z << 16), __uint_as_float(ekv.z & 0xffff0000u)};
    ek2[3] = (v2f){__uint_as_float(ekv.w << 16), __uint_as_float(ekv.w & 0xffff0000u)};
    // v slices via scalar pipe (wave-uniform global loads), positive sign
    v2f vv2[4];
#pragma unroll
    for (int p = 0; p < 4; ++p)
      vv2[p] = *(const v2f*)&v_att[d0 + p * 2];
#pragma unroll
    for (int qq = 0; qq < 4; ++qq) {
      const float4 e0 = *(const float4*)(qbase + qq * D_ATT + d0);
      const float4 e1 = *(const float4*)(qbase + qq * D_ATT + d0 + 4);
      const v2f dd0 = __builtin_elementwise_fma((v2f){e0.x, e0.y}, ek2[0], one2);
      const v2f dd1 = __builtin_elementwise_fma((v2f){e0.z, e0.w}, ek2[1], one2);
      const v2f dd2 = __builtin_elementwise_fma((v2f){e1.x, e1.y}, ek2[2], one2);
      const v2f dd3 = __builtin_elementwise_fma((v2f){e1.z, e1.w}, ek2[3], one2);
      const v2f Q1 = dd0 * dd1;
      const v2f Q2 = dd2 * dd3;
      const v2f R = Q1 * Q2;
      const float r = __builtin_amdgcn_rcpf(R.x * R.y);
      const v2f t = (v2f){r, r} * (v2f){R.y, R.x};
      const v2f iQ1 = t * Q2;
      const v2f iQ2 = t * Q1;
      accp[qq] = __builtin_elementwise_fma(vv2[0], iQ1 * dd1, accp[qq]);
      accp[qq] = __builtin_elementwise_fma(vv2[1], iQ1 * dd0, accp[qq]);
      accp[qq] = __builtin_elementwise_fma(vv2[2], iQ2 * dd3, accp[qq]);
      accp[qq] = __builtin_elementwise_fma(vv2[3], iQ2 * dd2, accp[qq]);
    }
  }

  const float cst = vsumc[0];
#pragma unroll
  for (int qq = 0; qq < 4; ++qq) {
    const int qrow = w * 4 + qq;
    const int q = qt * 16 + qrow;
    out[(size_t)(b * NUM_Q + q) * NUM_K + kt * 64 + k] =
        fmaf(-2.0f, accp[qq].x + accp[qq].y, cst + sblds[qrow * 64 + k]);
  }
}

extern "C" void kernel_launch(void* const* d_in, const int* in_sizes, int n_in,
                              void* d_out, int out_size, void* d_ws, size_t ws_size,
                              hipStream_t stream) {
  const float* query = (const float*)d_in[0];
  const float* key   = (const float*)d_in[1];
  const float* W_bq  = (const float*)d_in[2];
  const float* b_bq  = (const float*)d_in[3];
  const float* W_bk  = (const float*)d_in[4];
  const float* b_bk  = (const float*)d_in[5];
  const float* W_lq  = (const float*)d_in[6];
  const float* b_lq  = (const float*)d_in[7];
  const float* W_lk  = (const float*)d_in[8];
  const float* b_lk  = (const float*)d_in[9];
  const float* v_att = (const float*)d_in[10];
  const float* b_att = (const float*)d_in[11];

  // ws: eq f32 (256KB) | qb (128KB) | ek (1MB) | kb (1MB) | Wt2 (512KB) | vsumc
  float* eq = (float*)d_ws;
  uint16_t* qb = (uint16_t*)(eq + 512 * D_ATT);
  uint16_t* ek = qb + 512 * D_ATT;
  uint16_t* kb = ek + 4096 * D_ATT;
  uint16_t* Wt2 = kb + 4096 * D_ATT;
  float* vsumc = (float*)(Wt2 + 2 * 256 * 512);

  pack_w<<<64, 256, 0, stream>>>(W_lq, W_bq, W_lk, W_bk, v_att, b_att,
                                 Wt2, vsumc);
  proj_gemm<<<576, 256, 0, stream>>>(query, key, Wt2, b_lq, b_bq, b_lk, b_bk,
                                     eq, qb, ek, kb);
  fused_kernel<<<BSZ * 16 * 32, 256, 0, stream>>>(
      eq, qb, ek, kb, v_att, vsumc, (float*)d_out);
}

// Round 15
// 34.672 us; speedup vs baseline: 1.0633x; 1.0633x over previous
//
#include <hip/hip_runtime.h>
#include <hip/hip_bf16.h>
#include <cstdint>

#define DEV_INLINE __device__ __forceinline__

typedef __attribute__((ext_vector_type(8))) short short8v;   // 8 bf16 (4 VGPRs)
typedef __attribute__((ext_vector_type(4))) float f32x4;
typedef __attribute__((ext_vector_type(2))) float v2f;       // packed fp32 pair

constexpr int BSZ = 2, NUM_Q = 256, NUM_K = 2048, D_IN = 512, D_ATT = 128;
constexpr float S_ATT = 0.08838834764831845f;   // 1/sqrt(128)
constexpr float C2 = 2.8853900817779268f;       // 2*log2(e): exp2(C2*x) = e^{2x}

DEV_INLINE uint16_t f2bf(float f) {  // fp32 -> bf16 bits, round-nearest-even
  uint32_t u = __float_as_uint(f);
  return (uint16_t)((u + 0x7fffu + ((u >> 16) & 1u)) >> 16);
}

DEV_INLINE float fast_exp2(float x) {
#if __has_builtin(__builtin_amdgcn_exp2f)
  return __builtin_amdgcn_exp2f(x);
#else
  return __expf(0.6931471805599453f * x);
#endif
}

// ---------------------------------------------------------------------------
// pack_w (64 blocks): fragment-packed Wt2, chunk (mat,cb,s) = 64 lanes x
// 8 bf16; lane l: cols cb*16+(l&15), k = s*32+(l>>4)*8+j. Block 0 also does
// vsumc[0] = sum(v_att)+b_att.
// ---------------------------------------------------------------------------
__global__ __launch_bounds__(256) void pack_w(
    const float* __restrict__ Wlq, const float* __restrict__ Wbq,
    const float* __restrict__ Wlk, const float* __restrict__ Wbk,
    const float* __restrict__ v_att, const float* __restrict__ b_att,
    uint16_t* __restrict__ Wt2, float* __restrict__ vsumc) {
  __shared__ float xs[256 * 17];  // 17 KB, +1 pad
  const int bid = blockIdx.x;
  const int t = threadIdx.x;

  const int mat = bid >> 5, cb = (bid >> 1) & 15, kh = bid & 1;
  const float* W = (mat == 0) ? (cb < 8 ? Wlq : Wbq) : (cb < 8 ? Wlk : Wbk);
  const int cbase = (cb & 7) * 16;

#pragma unroll
  for (int i = 0; i < 4; ++i) {
    const int fq = t + i * 256;          // 1024 quads
    const int k = fq >> 2, c4 = (fq & 3) * 4;
    const float4 v = *(const float4*)&W[(size_t)(kh * 256 + k) * D_ATT + cbase + c4];
    xs[k * 17 + c4 + 0] = v.x;
    xs[k * 17 + c4 + 1] = v.y;
    xs[k * 17 + c4 + 2] = v.z;
    xs[k * 17 + c4 + 3] = v.w;
  }
  __syncthreads();

#pragma unroll
  for (int i = 0; i < 2; ++i) {
    const int e = t + i * 256;
    const int sl = e >> 6, l = e & 63;
    const int kb_ = sl * 32 + (l >> 4) * 8;
    const int c = l & 15;
    uint16_t o[8];
#pragma unroll
    for (int j = 0; j < 8; ++j) o[j] = f2bf(xs[(kb_ + j) * 17 + c]);
    const int sg = kh * 8 + sl;
    *(uint4*)(Wt2 + ((size_t)(mat * 16 + cb) * 16 + sg) * 512 + l * 8) =
        *(const uint4*)o;
  }

  if (bid == 0 && t < 64) {
    float s = v_att[t] + v_att[t + 64];
#pragma unroll
    for (int off = 32; off >= 1; off >>= 1) s += __shfl_down(s, off);
    if (t == 0) vsumc[0] = s + b_att[0];
  }
}

// ---------------------------------------------------------------------------
// proj_gemm (576 blocks x 256 thr): [query;key] (4608x512 fp32 -> bf16 during
// LDS staging) @ Wt2. Epilogue: eq = exp2(C2*ql) fp32; ek = bf16(exp2(C2*kl));
// qb bf16 (xS_ATT); kb bf16.
// Block = 4 waves sharing ONE 16-row A-tile (XOR-swizzled);
// rt = bid>>1, ct2 = (bid&1)*4 + wave.
// Frag maps (validated r3-r14): A row=lane&15, k=(lane>>4)*8+j; B col=lane&15;
// C/D col=lane&15, row=(lane>>4)*4+reg.
// ---------------------------------------------------------------------------
__global__ __launch_bounds__(256) void proj_gemm(
    const float* __restrict__ Xq, const float* __restrict__ Xk,
    const uint16_t* __restrict__ Wt2,
    const float* __restrict__ b_lq, const float* __restrict__ b_bq,
    const float* __restrict__ b_lk, const float* __restrict__ b_bk,
    float* __restrict__ eq, uint16_t* __restrict__ qb,
    uint16_t* __restrict__ ek, uint16_t* __restrict__ kb) {
  __shared__ __align__(16) unsigned char alds[16 * 1024];  // 16 rows x 512 bf16
  const int bid = blockIdx.x;           // 0..575
  const int t = threadIdx.x;
  const int l = t & 63;
  const int rt = bid >> 1;              // 0..287 (row-tile of 16)
  const int ct2 = (bid & 1) * 4 + (t >> 6);  // 0..7

  const bool isq = rt < 32;
  const int mat = isq ? 0 : 1;
  const int row0 = isq ? rt * 16 : (rt - 32) * 16;  // local row in q/k buffers
  const float* src = (isq ? Xq : Xk) + (size_t)row0 * D_IN;

  // stage A-tile: 1024 bf16 16B-chunks; chunk f: row=f>>6, c=f&63 (8 elems)
#pragma unroll
  for (int i = 0; i < 4; ++i) {
    const int f = t + i * 256;
    const int row = f >> 6, c = f & 63;
    const float* s8 = src + (size_t)row * D_IN + c * 8;
    const float4 a = *(const float4*)s8;
    const float4 b = *(const float4*)(s8 + 4);
    uint16_t o[8];
    o[0] = f2bf(a.x); o[1] = f2bf(a.y); o[2] = f2bf(a.z); o[3] = f2bf(a.w);
    o[4] = f2bf(b.x); o[5] = f2bf(b.y); o[6] = f2bf(b.z); o[7] = f2bf(b.w);
    *(uint4*)(alds + row * 1024 + ((c ^ (row & 7)) << 4)) = *(const uint4*)o;
  }
  __syncthreads();

  const uint16_t* wbase =
      Wt2 + ((size_t)(mat * 16 + ct2 * 2) * 16) * 512 + l * 8;
  const int arow = l & 15;

  f32x4 acc0 = {0.f, 0.f, 0.f, 0.f}, acc1 = {0.f, 0.f, 0.f, 0.f};
#pragma unroll 4
  for (int s = 0; s < 16; ++s) {
    const int chunk = (s * 4 + (l >> 4)) ^ (arow & 7);
    const short8v a = *(const short8v*)(alds + arow * 1024 + (chunk << 4));
    const short8v b0 = *(const short8v*)(wbase + (size_t)s * 512);
    const short8v b1 = *(const short8v*)(wbase + (size_t)(16 + s) * 512);
    acc0 = __builtin_amdgcn_mfma_f32_16x16x32_bf16(a, b0, acc0, 0, 0, 0);
    acc1 = __builtin_amdgcn_mfma_f32_16x16x32_bf16(a, b1, acc1, 0, 0, 0);
  }

  const int lrow4 = (l >> 4) * 4;
#pragma unroll
  for (int half = 0; half < 2; ++half) {
    const f32x4 acc = half ? acc1 : acc0;
    const int cbb = ct2 * 32 + half * 16;  // wave-uniform col-block base
    const int cl = (cbb + (l & 15)) & 127;
    float bias;
    if (isq) bias = (cbb < 128) ? b_lq[cl] : b_bq[cl];
    else     bias = (cbb < 128) ? b_lk[cl] : b_bk[cl];
#pragma unroll
    for (int jr = 0; jr < 4; ++jr) {
      const int row = row0 + lrow4 + jr;
      const float val = acc[jr] + bias;
      if (isq) {
        if (cbb < 128) eq[row * D_ATT + cl] = fast_exp2(C2 * val);
        else           qb[row * D_ATT + cl] = f2bf(val * S_ATT);
      } else {
        if (cbb < 128) ek[row * D_ATT + cl] = f2bf(fast_exp2(C2 * val));
        else           kb[row * D_ATT + cl] = f2bf(val);
      }
    }
  }
}

// ---------------------------------------------------------------------------
// fused (best r11 config): out = cst - 2*sum_d v_d/(1+eq*ek) + qb.kb
// 1024 blocks x 256 thr = 4 waves; tile 16 q x 64 k; eq AND v via wave-
// uniform scalar loads (s_load pipe); ek bf16 in LDS (swizzled). LDS 20 KB.
// Packed fp32 inner loop; pair-reciprocal (1 rcp per 4 elems).
// ---------------------------------------------------------------------------
__global__ __launch_bounds__(256) void fused_kernel(
    const float* __restrict__ eq_g, const uint16_t* __restrict__ qb_g,
    const uint16_t* __restrict__ ek_g, const uint16_t* __restrict__ kb_g,
    const float* __restrict__ v_att, const float* __restrict__ vsumc,
    float* __restrict__ out) {
  __shared__ __align__(16) unsigned char klds[64 * 256];  // ek bf16, swizzled
  __shared__ float sblds[16 * 64];                        // bilinear C, 4 KB

  const int tid = threadIdx.x;
  const int b = blockIdx.x >> 9;
  const int qt = (blockIdx.x >> 5) & 15;
  const int kt = blockIdx.x & 31;

  // --- stage ek tile (64 rows x 256B, XOR-swizzled 16B chunks) ---
  const uint4* ekg = (const uint4*)(ek_g + (size_t)(b * NUM_K + kt * 64) * D_ATT);
#pragma unroll
  for (int i = 0; i < 4; ++i) {
    const int f = tid + i * 256;
    const int kr = f >> 4, c = f & 15;
    *(uint4*)(klds + kr * 256 + ((c ^ (kr & 7)) << 4)) = ekg[f];
  }

  // --- bilinear via MFMA: wave w -> k-range [w*16, w*16+16) ---
  {
    const int l = tid & 63;
    const int w = tid >> 6;
    const uint16_t* ap =
        qb_g + (size_t)(b * NUM_Q + qt * 16 + (l & 15)) * D_ATT + (l >> 4) * 8;
    const uint16_t* bp =
        kb_g + (size_t)(b * NUM_K + kt * 64 + w * 16 + (l & 15)) * D_ATT + (l >> 4) * 8;
    f32x4 acc = {0.f, 0.f, 0.f, 0.f};
#pragma unroll
    for (int s = 0; s < 4; ++s) {
      const short8v a = *(const short8v*)(ap + s * 32);
      const short8v bb = *(const short8v*)(bp + s * 32);
      acc = __builtin_amdgcn_mfma_f32_16x16x32_bf16(a, bb, acc, 0, 0, 0);
    }
    const int col = w * 16 + (l & 15);
    const int r0 = (l >> 4) * 4;
#pragma unroll
    for (int jr = 0; jr < 4; ++jr) sblds[(r0 + jr) * 64 + col] = acc[jr];
  }
  __syncthreads();

  // --- linear path (packed fp32): thread = (k = tid&63, q-group tid>>6) ---
  const int k = tid & 63;
  const int w = tid >> 6;
  const int qoff =
      __builtin_amdgcn_readfirstlane((b * NUM_Q + qt * 16 + (tid >> 6) * 4) * D_ATT);
  const float* qbase = eq_g + qoff;

  const v2f one2 = {1.0f, 1.0f};
  v2f accp[4];
#pragma unroll
  for (int qq = 0; qq < 4; ++qq) accp[qq] = (v2f){0.f, 0.f};

  for (int d0 = 0; d0 < D_ATT; d0 += 8) {
    const int c = d0 >> 3;
    const uint4 ekv = *(const uint4*)(klds + k * 256 + ((c ^ (k & 7)) << 4));
    v2f ek2[4];
    ek2[0] = (v2f){__uint_as_float(ekv.x << 16), __uint_as_float(ekv.x & 0xffff0000u)};
    ek2[1] = (v2f){__uint_as_float(ekv.y << 16), __uint_as_float(ekv.y & 0xffff0000u)};
    ek2[2] = (v2f){__uint_as_float(ekv.z << 16), __uint_as_float(ekv.z & 0xffff0000u)};
    ek2[3] = (v2f){__uint_as_float(ekv.w << 16), __uint_as_float(ekv.w & 0xffff0000u)};
    // v slices via scalar pipe (wave-uniform global loads), positive sign
    v2f vv2[4];
#pragma unroll
    for (int p = 0; p < 4; ++p)
      vv2[p] = *(const v2f*)&v_att[d0 + p * 2];
#pragma unroll
    for (int qq = 0; qq < 4; ++qq) {
      const float4 e0 = *(const float4*)(qbase + qq * D_ATT + d0);
      const float4 e1 = *(const float4*)(qbase + qq * D_ATT + d0 + 4);
      v2f dd0 = __builtin_elementwise_fma((v2f){e0.x, e0.y}, ek2[0], one2);
      v2f dd1 = __builtin_elementwise_fma((v2f){e0.z, e0.w}, ek2[1], one2);
      v2f dd2 = __builtin_elementwise_fma((v2f){e1.x, e1.y}, ek2[2], one2);
      v2f dd3 = __builtin_elementwise_fma((v2f){e1.z, e1.w}, ek2[3], one2);
      {
        const v2f P = dd0 * dd1;
        const float r = __builtin_amdgcn_rcpf(P.x * P.y);
        const v2f t = (v2f){r, r} * (v2f){P.y, P.x};
        accp[qq] = __builtin_elementwise_fma(vv2[0], t * dd1, accp[qq]);
        accp[qq] = __builtin_elementwise_fma(vv2[1], t * dd0, accp[qq]);
      }
      {
        const v2f P = dd2 * dd3;
        const float r = __builtin_amdgcn_rcpf(P.x * P.y);
        const v2f t = (v2f){r, r} * (v2f){P.y, P.x};
        accp[qq] = __builtin_elementwise_fma(vv2[2], t * dd3, accp[qq]);
        accp[qq] = __builtin_elementwise_fma(vv2[3], t * dd2, accp[qq]);
      }
    }
  }

  const float cst = vsumc[0];
#pragma unroll
  for (int qq = 0; qq < 4; ++qq) {
    const int qrow = w * 4 + qq;
    const int q = qt * 16 + qrow;
    out[(size_t)(b * NUM_Q + q) * NUM_K + kt * 64 + k] =
        fmaf(-2.0f, accp[qq].x + accp[qq].y, cst + sblds[qrow * 64 + k]);
  }
}

extern "C" void kernel_launch(void* const* d_in, const int* in_sizes, int n_in,
                              void* d_out, int out_size, void* d_ws, size_t ws_size,
                              hipStream_t stream) {
  const float* query = (const float*)d_in[0];
  const float* key   = (const float*)d_in[1];
  const float* W_bq  = (const float*)d_in[2];
  const float* b_bq  = (const float*)d_in[3];
  const float* W_bk  = (const float*)d_in[4];
  const float* b_bk  = (const float*)d_in[5];
  const float* W_lq  = (const float*)d_in[6];
  const float* b_lq  = (const float*)d_in[7];
  const float* W_lk  = (const float*)d_in[8];
  const float* b_lk  = (const float*)d_in[9];
  const float* v_att = (const float*)d_in[10];
  const float* b_att = (const float*)d_in[11];

  // ws: eq f32 (256KB) | qb (128KB) | ek (1MB) | kb (1MB) | Wt2 (512KB) | vsumc
  float* eq = (float*)d_ws;
  uint16_t* qb = (uint16_t*)(eq + 512 * D_ATT);
  uint16_t* ek = qb + 512 * D_ATT;
  uint16_t* kb = ek + 4096 * D_ATT;
  uint16_t* Wt2 = kb + 4096 * D_ATT;
  float* vsumc = (float*)(Wt2 + 2 * 256 * 512);

  pack_w<<<64, 256, 0, stream>>>(W_lq, W_bq, W_lk, W_bk, v_att, b_att,
                                 Wt2, vsumc);
  proj_gemm<<<576, 256, 0, stream>>>(query, key, Wt2, b_lq, b_bq, b_lk, b_bk,
                                     eq, qb, ek, kb);
  fused_kernel<<<BSZ * 16 * 32, 256, 0, stream>>>(
      eq, qb, ek, kb, v_att, vsumc, (float*)d_out);
}